// Round 16
// baseline (87.410 us; speedup 1.0000x reference)
//
#include <hip/hip_runtime.h>
#include <hip/hip_fp16.h>
#include <math.h>

#define N_PRED 12
#define B      256
#define N_NEG  128
#define D      512
#define NROWS  ((N_PRED + 1) * B)   // 3328 bank rows
#define NTB    (N_PRED * B)         // 3072 (t,b) pairs
#define LOG2E  1.4426950408889634f
#define LN2    0.6931471805599453f

typedef float f2 __attribute__((ext_vector_type(2)));

__device__ __forceinline__ float ex2(float x) { return __builtin_amdgcn_exp2f(x); }

// ---------------- conversion: fp32 bank -> fp16 bank (3.4 MB, L2-resident) --
__global__ __launch_bounds__(256) void conv_kernel(
    const float* __restrict__ lp, const float* __restrict__ ps,
    __half* __restrict__ hbank)
{
    const int e8 = blockIdx.x * 256 + threadIdx.x;  // 8-elem chunk id
    const int e  = e8 * 8;
    const float* src = (e < B * D) ? (lp + e) : (ps + (e - B * D));
    float4 a = ((const float4*)src)[0];
    float4 b = ((const float4*)src)[1];
    union { uint4 u; __half2 h[4]; } o;
    o.h[0] = __floats2half2_rn(a.x, a.y);
    o.h[1] = __floats2half2_rn(a.z, a.w);
    o.h[2] = __floats2half2_rn(b.x, b.y);
    o.h[3] = __floats2half2_rn(b.z, b.w);
    ((uint4*)hbank)[e8] = o.u;
}

// exp-sum of this lane's 8 contiguous fp16 elems (one uint4) against p2[0..3].
__device__ __forceinline__ float expsum8(uint4 w, const f2* __restrict__ p2) {
    const __half2* hp = (const __half2*)&w;
    float2 f0 = __half22float2(hp[0]);
    float2 f1 = __half22float2(hp[1]);
    float2 fv = __half22float2(hp[2]);
    float2 f3 = __half22float2(hp[3]);
    f2 m0 = p2[0] * f2{f0.x, f0.y};
    f2 m1 = p2[1] * f2{f1.x, f1.y};
    f2 m2 = p2[2] * f2{fv.x, fv.y};
    f2 m3 = p2[3] * f2{f3.x, f3.y};
    f2 a0 = f2{ex2(m0.x), ex2(m0.y)} + f2{ex2(m1.x), ex2(m1.y)};
    f2 a1 = f2{ex2(m2.x), ex2(m2.y)} + f2{ex2(m3.x), ex2(m3.y)};
    f2 a  = a0 + a1;
    return a.x + a.y;
}

// ---------------- main kernel: co-resident half-waves, integrated ----------
// 3072 blocks x 128 threads = 6144 independent waves = 12 blocks/CU =
// 24 waves/CU: the ENTIRE grid is co-resident in one dispatch round (R15's
// 6144x128 grid needed 1.5 rounds -> half-empty second round). Each wave
// owns 64 negs of one (t,b); no barrier until the final combine. Whole fp16
// row = 64 lanes x one uint4; batch-8 loads + 8-wide butterfly (R13-R15
// shape). Margin decision + exact fp32 redo INSIDE the kernel (vs R15's
// separate launches costing ~30us).
__global__ __launch_bounds__(128) void fk_main(
    const float* __restrict__ lp,        // (13,256,512) fp32
    const float* __restrict__ ps,        // (12,256,512) fp32
    const int*   __restrict__ time_idx,  // (12,256,128)
    const int*   __restrict__ batch_idx, // (12,256,128)
    const __half* __restrict__ hbank,    // (3328,512) fp16 bank
    float* __restrict__ per_step,        // (3072)
    float* __restrict__ flags)           // (3072)
{
    const int tb   = blockIdx.x;
    const int t    = tb >> 8;
    const int b    = tb & (B - 1);
    const int tid  = threadIdx.x;
    const int wave = tid >> 6;           // 0..1
    const int lane = tid & 63;

    __shared__ float s_sum[2];
    __shared__ float s_max[2];
    __shared__ int   s_oki[2];
    __shared__ int   s_flag;

    // this wave's 64 (ti,bi) pairs live in lane registers
    const int ib  = tb * N_NEG + wave * 64;
    const int tiv = time_idx[ib + lane];
    const int biv = batch_idx[ib + lane];

    // pred slice: lane owns elems [8*lane, 8*lane+8), pre-scaled by log2(e)
    const float4* pred4 = (const float4*)(lp + ((size_t)(t + 1) * B + b) * D);
    f2 p2[4];
    {
        float4 pa = pred4[2 * lane];
        float4 pb = pred4[2 * lane + 1];
        p2[0] = f2{pa.x * LOG2E, pa.y * LOG2E};
        p2[1] = f2{pa.z * LOG2E, pa.w * LOG2E};
        p2[2] = f2{pb.x * LOG2E, pb.y * LOG2E};
        p2[3] = f2{pb.z * LOG2E, pb.w * LOG2E};
    }

    // fk_pos from the fp16 bank row (both waves redundantly; 1/65 of work)
    float fk_pos;
    {
        uint4 wp = ((const uint4*)(hbank + ((size_t)(t + 1) * B + b) * D))[lane];
        float s = expsum8(wp, p2);
#pragma unroll
        for (int off = 1; off < 64; off <<= 1) s += __shfl_xor(s, off, 64);
        fk_pos = s;
    }

    float negsum = 0.0f, maxfk = 0.0f;

#pragma unroll 1
    for (int bt = 0; bt < 8; ++bt) {
        uint4 w0, w1, w2, w3, w4, w5, w6, w7;
#define ROWLD(W, I)                                                           \
        {                                                                     \
            const int n_  = bt * 8 + (I);                                     \
            const int ti_ = __shfl(tiv, n_, 64);                              \
            const int bi_ = __shfl(biv, n_, 64);                              \
            W = ((const uint4*)(hbank + ((size_t)(ti_ * B + bi_)) * D))[lane]; \
        }
        ROWLD(w0, 0) ROWLD(w1, 1) ROWLD(w2, 2) ROWLD(w3, 3)
        ROWLD(w4, 4) ROWLD(w5, 5) ROWLD(w6, 6) ROWLD(w7, 7)
#undef ROWLD

        float pk[8];
        pk[0] = expsum8(w0, p2); pk[1] = expsum8(w1, p2);
        pk[2] = expsum8(w2, p2); pk[3] = expsum8(w3, p2);
        pk[4] = expsum8(w4, p2); pk[5] = expsum8(w5, p2);
        pk[6] = expsum8(w6, p2); pk[7] = expsum8(w7, p2);

        // one butterfly over all 8 row-sums: 6 levels x 8 independent ops
#pragma unroll
        for (int off = 1; off < 64; off <<= 1) {
#pragma unroll
            for (int i = 0; i < 8; ++i)
                pk[i] += __shfl_xor(pk[i], off, 64);
        }
#pragma unroll
        for (int i = 0; i < 8; ++i) {
            negsum += pk[i];
            maxfk   = fmaxf(maxfk, pk[i]);
        }
    }

    if (lane == 0) { s_sum[wave] = negsum; s_max[wave] = maxfk; }
    __syncthreads();
    if (tid == 0) {
        const float tn = s_sum[0] + s_sum[1];
        const float mx = fmaxf(s_max[0], s_max[1]);
        per_step[tb] = (__builtin_amdgcn_logf(fk_pos) -
                        __builtin_amdgcn_logf(fk_pos + tn)) * LN2;
        const float margin = fk_pos - mx;
        const int near = fabsf(margin) <= 0.08f * fmaxf(fk_pos, mx);
        s_flag = near;
        if (!near) flags[tb] = (margin > 0.0f) ? 1.0f : 0.0f;
    }
    __syncthreads();

    if (s_flag) {
        // exact fp32 redo of the comparison (rare). Each wave: its 64 negs.
        float4 pl0 = pred4[lane];
        float4 pl1 = pred4[lane + 64];
        pl0.x *= LOG2E; pl0.y *= LOG2E; pl0.z *= LOG2E; pl0.w *= LOG2E;
        pl1.x *= LOG2E; pl1.y *= LOG2E; pl1.z *= LOG2E; pl1.w *= LOG2E;

        const float4* pr = (const float4*)(ps + ((size_t)t * B + b) * D);
        float4 ya = pr[lane], yb = pr[lane + 64];
        float sp = ex2(pl0.x * ya.x) + ex2(pl0.y * ya.y) + ex2(pl0.z * ya.z) + ex2(pl0.w * ya.w)
                 + ex2(pl1.x * yb.x) + ex2(pl1.y * yb.y) + ex2(pl1.z * yb.z) + ex2(pl1.w * yb.w);
#pragma unroll
        for (int off = 1; off < 64; off <<= 1) sp += __shfl_xor(sp, off, 64);
        const float fkpos32 = sp;

        int okx = 1;
#pragma unroll 1
        for (int n = 0; n < 64; ++n) {
            const int ti = __shfl(tiv, n, 64);
            const int bi = __shfl(biv, n, 64);
            const float* row = (ti == 0) ? (lp + (size_t)bi * D)
                                         : (ps + ((size_t)(ti - 1) * B + bi) * D);
            const float4* r4 = (const float4*)row;
            float4 za = r4[lane], zb = r4[lane + 64];
            float s = ex2(pl0.x * za.x) + ex2(pl0.y * za.y) + ex2(pl0.z * za.z) + ex2(pl0.w * za.w)
                    + ex2(pl1.x * zb.x) + ex2(pl1.y * zb.y) + ex2(pl1.z * zb.z) + ex2(pl1.w * zb.w);
#pragma unroll
            for (int off = 1; off < 64; off <<= 1) s += __shfl_xor(s, off, 64);
            okx &= (fkpos32 > s) ? 1 : 0;
        }
        if (lane == 0) s_oki[wave] = okx;
        __syncthreads();
        if (tid == 0) flags[tb] = (float)(s_oki[0] & s_oki[1]);
    }
}

// ---------------- fallback: proven R5 fp32 kernel (used if ws too small) ---
__global__ __launch_bounds__(256) void fk_kernel_f32(
    const float* __restrict__ lp, const float* __restrict__ ps,
    const int* __restrict__ time_idx, const int* __restrict__ batch_idx,
    float* __restrict__ per_step, float* __restrict__ flags)
{
    const int tb   = blockIdx.x;
    const int t    = tb >> 8;
    const int b    = tb & (B - 1);
    const int tid  = threadIdx.x;
    const int wave = tid >> 6;
    const int lane = tid & 63;
    const int q    = lane & 15;
    const int g    = lane >> 4;

    __shared__ const float* s_row[N_NEG];
    __shared__ float s_sum[4];
    __shared__ int   s_ok[4];

    const int idx_base = (t * B + b) * N_NEG;
    if (tid < N_NEG) {
        const int ti = time_idx[idx_base + tid];
        const int bi = batch_idx[idx_base + tid];
        s_row[tid] = (ti == 0) ? (lp + (size_t)bi * D)
                               : (ps + ((size_t)(ti - 1) * B + bi) * D);
    }

    const float4* pred4 = (const float4*)(lp + ((size_t)(t + 1) * B + b) * D) + q;
    f2 p2[16];
#pragma unroll
    for (int j = 0; j < 8; ++j) {
        float4 v = pred4[j * 16];
        p2[2 * j]     = f2{v.x * LOG2E, v.y * LOG2E};
        p2[2 * j + 1] = f2{v.z * LOG2E, v.w * LOG2E};
    }

    float fk_pos;
    {
        const float4* pos4 = (const float4*)(ps + ((size_t)t * B + b) * D) + q;
        f2 acc = {0.f, 0.f};
#pragma unroll
        for (int j = 0; j < 8; ++j) {
            float4 y = pos4[j * 16];
            f2 m0 = p2[2 * j] * f2{y.x, y.y};
            f2 m1 = p2[2 * j + 1] * f2{y.z, y.w};
            acc += f2{ex2(m0.x), ex2(m0.y)};
            acc += f2{ex2(m1.x), ex2(m1.y)};
        }
        float s = acc.x + acc.y;
#pragma unroll
        for (int off = 1; off < 16; off <<= 1) s += __shfl_xor(s, off, 64);
        fk_pos = s;
    }

    __syncthreads();

    float negsum = 0.0f;
    bool  all_ok = true;
#pragma unroll 2
    for (int it = 0; it < 8; ++it) {
        const int n = wave * 32 + it * 4 + g;
        const float4* row4 = (const float4*)s_row[n] + q;
        f2 acc = {0.f, 0.f};
#pragma unroll
        for (int j = 0; j < 8; ++j) {
            float4 y = row4[j * 16];
            f2 m0 = p2[2 * j] * f2{y.x, y.y};
            f2 m1 = p2[2 * j + 1] * f2{y.z, y.w};
            acc += f2{ex2(m0.x), ex2(m0.y)};
            acc += f2{ex2(m1.x), ex2(m1.y)};
        }
        float fk = acc.x + acc.y;
#pragma unroll
        for (int off = 1; off < 16; off <<= 1) fk += __shfl_xor(fk, off, 64);
        negsum += fk;
        all_ok  = all_ok && (fk_pos > fk);
    }

    const int wave_ok = __all(all_ok ? 1 : 0);
    float ns = negsum;
#pragma unroll
    for (int off = 16; off < 64; off <<= 1) ns += __shfl_xor(ns, off, 64);

    if (lane == 0) { s_sum[wave] = ns; s_ok[wave] = wave_ok; }
    __syncthreads();
    if (tid == 0) {
        float total_neg = (s_sum[0] + s_sum[1]) + (s_sum[2] + s_sum[3]);
        int   ok        = s_ok[0] & s_ok[1] & s_ok[2] & s_ok[3];
        float total     = fk_pos + total_neg;
        per_step[tb] = (__builtin_amdgcn_logf(fk_pos) - __builtin_amdgcn_logf(total)) * LN2;
        flags[tb]    = (float)ok;
    }
}

// ---------------- final reduce --------------------------------------------
__global__ __launch_bounds__(256) void reduce_kernel(
    const float* __restrict__ per_step,
    const float* __restrict__ flags,
    float* __restrict__ out)
{
    const int tid = threadIdx.x;
    const int j   = blockIdx.x;
    __shared__ float sh[4];

    float s = 0.0f;
    if (j == 0) {
#pragma unroll
        for (int t = 0; t < N_PRED; ++t) s += per_step[t * B + tid];
    } else {
        s = flags[(j - 1) * B + tid];
    }
#pragma unroll
    for (int off = 32; off > 0; off >>= 1) s += __shfl_xor(s, off, 64);
    if ((tid & 63) == 0) sh[tid >> 6] = s;
    __syncthreads();
    if (tid == 0) {
        float tot = (sh[0] + sh[1]) + (sh[2] + sh[3]);
        if (j == 0)
            out[0] = tot * (1.0f / ((float)(N_NEG + 1) * N_PRED * B));
        else
            out[j] = tot;
    }
}

extern "C" void kernel_launch(void* const* d_in, const int* in_sizes, int n_in,
                              void* d_out, int out_size, void* d_ws, size_t ws_size,
                              hipStream_t stream) {
    const float* lp        = (const float*)d_in[0];
    const float* ps        = (const float*)d_in[1];
    const int*   time_idx  = (const int*)d_in[2];
    const int*   batch_idx = (const int*)d_in[3];
    float* out = (float*)d_out;

    const size_t hbytes = (size_t)NROWS * D * sizeof(__half);          // 3.4 MB
    const size_t need   = hbytes + 2 * (size_t)NTB * sizeof(float);

    if (ws_size >= need) {
        __half* hbank    = (__half*)d_ws;
        float*  per_step = (float*)((char*)d_ws + hbytes);
        float*  flags    = per_step + NTB;

        conv_kernel<<<NROWS * D / 8 / 256, 256, 0, stream>>>(lp, ps, hbank);
        fk_main<<<NTB, 128, 0, stream>>>(lp, ps, time_idx, batch_idx, hbank,
                                         per_step, flags);
        reduce_kernel<<<1 + N_PRED, 256, 0, stream>>>(per_step, flags, out);
    } else {
        float* per_step = (float*)d_ws;
        float* flags    = per_step + NTB;
        fk_kernel_f32<<<NTB, 256, 0, stream>>>(lp, ps, time_idx, batch_idx,
                                               per_step, flags);
        reduce_kernel<<<1 + N_PRED, 256, 0, stream>>>(per_step, flags, out);
    }
}

// Round 17
// 56.140 us; speedup vs baseline: 1.5570x; 1.5570x over previous
//
#include <hip/hip_runtime.h>
#include <hip/hip_fp16.h>
#include <math.h>

#define N_PRED 12
#define B      256
#define N_NEG  128
#define D      512
#define NROWS  ((N_PRED + 1) * B)   // 3328 bank rows
#define NTB    (N_PRED * B)         // 3072 (t,b) pairs
#define LOG2E  1.4426950408889634f
#define LN2    0.6931471805599453f
#define BANDF  0.06f                 // candidate band: 2.5x the fp16 two-sided err bound

typedef float f2 __attribute__((ext_vector_type(2)));

__device__ __forceinline__ float ex2(float x) { return __builtin_amdgcn_exp2f(x); }

// ---------------- conversion: fp32 bank -> fp16 bank (3.4 MB, L2-resident) --
__global__ __launch_bounds__(256) void conv_kernel(
    const float* __restrict__ lp, const float* __restrict__ ps,
    __half* __restrict__ hbank)
{
    const int e8 = blockIdx.x * 256 + threadIdx.x;  // 8-elem chunk id
    const int e  = e8 * 8;
    const float* src = (e < B * D) ? (lp + e) : (ps + (e - B * D));
    float4 a = ((const float4*)src)[0];
    float4 b = ((const float4*)src)[1];
    union { uint4 u; __half2 h[4]; } o;
    o.h[0] = __floats2half2_rn(a.x, a.y);
    o.h[1] = __floats2half2_rn(a.z, a.w);
    o.h[2] = __floats2half2_rn(b.x, b.y);
    o.h[3] = __floats2half2_rn(b.z, b.w);
    ((uint4*)hbank)[e8] = o.u;
}

// exp-sum of this lane's 8 contiguous fp16 elems (one uint4) against p2[0..3].
__device__ __forceinline__ float expsum8(uint4 w, const f2* __restrict__ p2) {
    const __half2* hp = (const __half2*)&w;
    float2 f0 = __half22float2(hp[0]);
    float2 f1 = __half22float2(hp[1]);
    float2 fv = __half22float2(hp[2]);
    float2 f3 = __half22float2(hp[3]);
    f2 m0 = p2[0] * f2{f0.x, f0.y};
    f2 m1 = p2[1] * f2{f1.x, f1.y};
    f2 m2 = p2[2] * f2{fv.x, fv.y};
    f2 m3 = p2[3] * f2{f3.x, f3.y};
    f2 a0 = f2{ex2(m0.x), ex2(m0.y)} + f2{ex2(m1.x), ex2(m1.y)};
    f2 a1 = f2{ex2(m2.x), ex2(m2.y)} + f2{ex2(m3.x), ex2(m3.y)};
    f2 a  = a0 + a1;
    return a.x + a.y;
}

// ---------------- main kernel: co-resident half-waves + candidate redo -----
// 3072 blocks x 128 threads = 6144 independent waves = 12 blocks/CU =
// 24 waves/CU: whole grid co-resident in ONE dispatch round. Each wave owns
// 64 negs; whole fp16 row = 64 lanes x one uint4; batch-8 + 8-wide butterfly.
// Per-neg fp16 fk values are kept in LDS; the exact fp32 redo runs ONLY for
// blocks whose win/lose margin is inside a 6% band AND only for the 1-4
// candidate negs inside that band (R16's full-128-row redo created a 50us
// straggler tail -> 21% avg occupancy).
__global__ __launch_bounds__(128) void fk_main(
    const float* __restrict__ lp,        // (13,256,512) fp32
    const float* __restrict__ ps,        // (12,256,512) fp32
    const int*   __restrict__ time_idx,  // (12,256,128)
    const int*   __restrict__ batch_idx, // (12,256,128)
    const __half* __restrict__ hbank,    // (3328,512) fp16 bank
    float* __restrict__ per_step,        // (3072)
    float* __restrict__ flags)           // (3072)
{
    const int tb   = blockIdx.x;
    const int t    = tb >> 8;
    const int b    = tb & (B - 1);
    const int tid  = threadIdx.x;
    const int wave = tid >> 6;           // 0..1
    const int lane = tid & 63;

    __shared__ float s_fk[N_NEG];
    __shared__ float s_sum[2];
    __shared__ float s_max[2];
    __shared__ int   s_oki[2];
    __shared__ int   s_flag;
    __shared__ float s_thr;

    // this wave's 64 (ti,bi) pairs live in lane registers
    const int ib  = tb * N_NEG + wave * 64;
    const int tiv = time_idx[ib + lane];
    const int biv = batch_idx[ib + lane];

    // pred slice: lane owns elems [8*lane, 8*lane+8), pre-scaled by log2(e)
    const float4* pred4 = (const float4*)(lp + ((size_t)(t + 1) * B + b) * D);
    f2 p2[4];
    {
        float4 pa = pred4[2 * lane];
        float4 pb = pred4[2 * lane + 1];
        p2[0] = f2{pa.x * LOG2E, pa.y * LOG2E};
        p2[1] = f2{pa.z * LOG2E, pa.w * LOG2E};
        p2[2] = f2{pb.x * LOG2E, pb.y * LOG2E};
        p2[3] = f2{pb.z * LOG2E, pb.w * LOG2E};
    }

    // fk_pos from the fp16 bank row (both waves redundantly; 1/65 of work)
    float fk_pos;
    {
        uint4 wp = ((const uint4*)(hbank + ((size_t)(t + 1) * B + b) * D))[lane];
        float s = expsum8(wp, p2);
#pragma unroll
        for (int off = 1; off < 64; off <<= 1) s += __shfl_xor(s, off, 64);
        fk_pos = s;
    }

    float negsum = 0.0f, maxfk = 0.0f;

#pragma unroll 1
    for (int bt = 0; bt < 8; ++bt) {
        uint4 w0, w1, w2, w3, w4, w5, w6, w7;
#define ROWLD(W, I)                                                           \
        {                                                                     \
            const int n_  = bt * 8 + (I);                                     \
            const int ti_ = __shfl(tiv, n_, 64);                              \
            const int bi_ = __shfl(biv, n_, 64);                              \
            W = ((const uint4*)(hbank + ((size_t)(ti_ * B + bi_)) * D))[lane]; \
        }
        ROWLD(w0, 0) ROWLD(w1, 1) ROWLD(w2, 2) ROWLD(w3, 3)
        ROWLD(w4, 4) ROWLD(w5, 5) ROWLD(w6, 6) ROWLD(w7, 7)
#undef ROWLD

        float pk[8];
        pk[0] = expsum8(w0, p2); pk[1] = expsum8(w1, p2);
        pk[2] = expsum8(w2, p2); pk[3] = expsum8(w3, p2);
        pk[4] = expsum8(w4, p2); pk[5] = expsum8(w5, p2);
        pk[6] = expsum8(w6, p2); pk[7] = expsum8(w7, p2);

        // one butterfly over all 8 row-sums: 6 levels x 8 independent ops
#pragma unroll
        for (int off = 1; off < 64; off <<= 1) {
#pragma unroll
            for (int i = 0; i < 8; ++i)
                pk[i] += __shfl_xor(pk[i], off, 64);
        }
        if (lane == 0) {
#pragma unroll
            for (int i = 0; i < 8; ++i)
                s_fk[wave * 64 + bt * 8 + i] = pk[i];
        }
#pragma unroll
        for (int i = 0; i < 8; ++i) {
            negsum += pk[i];
            maxfk   = fmaxf(maxfk, pk[i]);
        }
    }

    if (lane == 0) { s_sum[wave] = negsum; s_max[wave] = maxfk; }
    __syncthreads();
    if (tid == 0) {
        const float tn = s_sum[0] + s_sum[1];
        const float mx = fmaxf(s_max[0], s_max[1]);
        per_step[tb] = (__builtin_amdgcn_logf(fk_pos) -
                        __builtin_amdgcn_logf(fk_pos + tn)) * LN2;
        const float band = BANDF * fmaxf(fk_pos, mx);
        if (mx > fk_pos + band)       { flags[tb] = 0.0f; s_flag = 0; }
        else if (mx < fk_pos - band)  { flags[tb] = 1.0f; s_flag = 0; }
        else { s_flag = 1; s_thr = fk_pos - band; }
    }
    __syncthreads();

    if (s_flag) {
        // exact fp32 redo for the FEW candidate negs only (plus fk_pos)
        float4 pl0 = pred4[lane];
        float4 pl1 = pred4[lane + 64];
        pl0.x *= LOG2E; pl0.y *= LOG2E; pl0.z *= LOG2E; pl0.w *= LOG2E;
        pl1.x *= LOG2E; pl1.y *= LOG2E; pl1.z *= LOG2E; pl1.w *= LOG2E;

        const float4* pr = (const float4*)(ps + ((size_t)t * B + b) * D);
        float4 ya = pr[lane], yb = pr[lane + 64];
        float sp = ex2(pl0.x * ya.x) + ex2(pl0.y * ya.y) + ex2(pl0.z * ya.z) + ex2(pl0.w * ya.w)
                 + ex2(pl1.x * yb.x) + ex2(pl1.y * yb.y) + ex2(pl1.z * yb.z) + ex2(pl1.w * yb.w);
#pragma unroll
        for (int off = 1; off < 64; off <<= 1) sp += __shfl_xor(sp, off, 64);
        const float fkpos32 = sp;

        // candidate mask over this wave's 64 negs (lane n <-> neg wave*64+n)
        const float thr = s_thr;
        unsigned long long m = __ballot(s_fk[wave * 64 + lane] >= thr);

        int okx = 1;
        while (m) {
            const int n = (int)__builtin_ctzll(m);
            m &= m - 1;
            const int ti = __shfl(tiv, n, 64);
            const int bi = __shfl(biv, n, 64);
            const float* row = (ti == 0) ? (lp + (size_t)bi * D)
                                         : (ps + ((size_t)(ti - 1) * B + bi) * D);
            const float4* r4 = (const float4*)row;
            float4 za = r4[lane], zb = r4[lane + 64];
            float s = ex2(pl0.x * za.x) + ex2(pl0.y * za.y) + ex2(pl0.z * za.z) + ex2(pl0.w * za.w)
                    + ex2(pl1.x * zb.x) + ex2(pl1.y * zb.y) + ex2(pl1.z * zb.z) + ex2(pl1.w * zb.w);
#pragma unroll
            for (int off = 1; off < 64; off <<= 1) s += __shfl_xor(s, off, 64);
            okx &= (fkpos32 > s) ? 1 : 0;
        }
        if (lane == 0) s_oki[wave] = okx;
        __syncthreads();
        if (tid == 0) flags[tb] = (float)(s_oki[0] & s_oki[1]);
    }
}

// ---------------- fallback: proven R5 fp32 kernel (used if ws too small) ---
__global__ __launch_bounds__(256) void fk_kernel_f32(
    const float* __restrict__ lp, const float* __restrict__ ps,
    const int* __restrict__ time_idx, const int* __restrict__ batch_idx,
    float* __restrict__ per_step, float* __restrict__ flags)
{
    const int tb   = blockIdx.x;
    const int t    = tb >> 8;
    const int b    = tb & (B - 1);
    const int tid  = threadIdx.x;
    const int wave = tid >> 6;
    const int lane = tid & 63;
    const int q    = lane & 15;
    const int g    = lane >> 4;

    __shared__ const float* s_row[N_NEG];
    __shared__ float s_sum[4];
    __shared__ int   s_ok[4];

    const int idx_base = (t * B + b) * N_NEG;
    if (tid < N_NEG) {
        const int ti = time_idx[idx_base + tid];
        const int bi = batch_idx[idx_base + tid];
        s_row[tid] = (ti == 0) ? (lp + (size_t)bi * D)
                               : (ps + ((size_t)(ti - 1) * B + bi) * D);
    }

    const float4* pred4 = (const float4*)(lp + ((size_t)(t + 1) * B + b) * D) + q;
    f2 p2[16];
#pragma unroll
    for (int j = 0; j < 8; ++j) {
        float4 v = pred4[j * 16];
        p2[2 * j]     = f2{v.x * LOG2E, v.y * LOG2E};
        p2[2 * j + 1] = f2{v.z * LOG2E, v.w * LOG2E};
    }

    float fk_pos;
    {
        const float4* pos4 = (const float4*)(ps + ((size_t)t * B + b) * D) + q;
        f2 acc = {0.f, 0.f};
#pragma unroll
        for (int j = 0; j < 8; ++j) {
            float4 y = pos4[j * 16];
            f2 m0 = p2[2 * j] * f2{y.x, y.y};
            f2 m1 = p2[2 * j + 1] * f2{y.z, y.w};
            acc += f2{ex2(m0.x), ex2(m0.y)};
            acc += f2{ex2(m1.x), ex2(m1.y)};
        }
        float s = acc.x + acc.y;
#pragma unroll
        for (int off = 1; off < 16; off <<= 1) s += __shfl_xor(s, off, 64);
        fk_pos = s;
    }

    __syncthreads();

    float negsum = 0.0f;
    bool  all_ok = true;
#pragma unroll 2
    for (int it = 0; it < 8; ++it) {
        const int n = wave * 32 + it * 4 + g;
        const float4* row4 = (const float4*)s_row[n] + q;
        f2 acc = {0.f, 0.f};
#pragma unroll
        for (int j = 0; j < 8; ++j) {
            float4 y = row4[j * 16];
            f2 m0 = p2[2 * j] * f2{y.x, y.y};
            f2 m1 = p2[2 * j + 1] * f2{y.z, y.w};
            acc += f2{ex2(m0.x), ex2(m0.y)};
            acc += f2{ex2(m1.x), ex2(m1.y)};
        }
        float fk = acc.x + acc.y;
#pragma unroll
        for (int off = 1; off < 16; off <<= 1) fk += __shfl_xor(fk, off, 64);
        negsum += fk;
        all_ok  = all_ok && (fk_pos > fk);
    }

    const int wave_ok = __all(all_ok ? 1 : 0);
    float ns = negsum;
#pragma unroll
    for (int off = 16; off < 64; off <<= 1) ns += __shfl_xor(ns, off, 64);

    if (lane == 0) { s_sum[wave] = ns; s_ok[wave] = wave_ok; }
    __syncthreads();
    if (tid == 0) {
        float total_neg = (s_sum[0] + s_sum[1]) + (s_sum[2] + s_sum[3]);
        int   ok        = s_ok[0] & s_ok[1] & s_ok[2] & s_ok[3];
        float total     = fk_pos + total_neg;
        per_step[tb] = (__builtin_amdgcn_logf(fk_pos) - __builtin_amdgcn_logf(total)) * LN2;
        flags[tb]    = (float)ok;
    }
}

// ---------------- final reduce --------------------------------------------
__global__ __launch_bounds__(256) void reduce_kernel(
    const float* __restrict__ per_step,
    const float* __restrict__ flags,
    float* __restrict__ out)
{
    const int tid = threadIdx.x;
    const int j   = blockIdx.x;
    __shared__ float sh[4];

    float s = 0.0f;
    if (j == 0) {
#pragma unroll
        for (int t = 0; t < N_PRED; ++t) s += per_step[t * B + tid];
    } else {
        s = flags[(j - 1) * B + tid];
    }
#pragma unroll
    for (int off = 32; off > 0; off >>= 1) s += __shfl_xor(s, off, 64);
    if ((tid & 63) == 0) sh[tid >> 6] = s;
    __syncthreads();
    if (tid == 0) {
        float tot = (sh[0] + sh[1]) + (sh[2] + sh[3]);
        if (j == 0)
            out[0] = tot * (1.0f / ((float)(N_NEG + 1) * N_PRED * B));
        else
            out[j] = tot;
    }
}

extern "C" void kernel_launch(void* const* d_in, const int* in_sizes, int n_in,
                              void* d_out, int out_size, void* d_ws, size_t ws_size,
                              hipStream_t stream) {
    const float* lp        = (const float*)d_in[0];
    const float* ps        = (const float*)d_in[1];
    const int*   time_idx  = (const int*)d_in[2];
    const int*   batch_idx = (const int*)d_in[3];
    float* out = (float*)d_out;

    const size_t hbytes = (size_t)NROWS * D * sizeof(__half);          // 3.4 MB
    const size_t need   = hbytes + 2 * (size_t)NTB * sizeof(float);

    if (ws_size >= need) {
        __half* hbank    = (__half*)d_ws;
        float*  per_step = (float*)((char*)d_ws + hbytes);
        float*  flags    = per_step + NTB;

        conv_kernel<<<NROWS * D / 8 / 256, 256, 0, stream>>>(lp, ps, hbank);
        fk_main<<<NTB, 128, 0, stream>>>(lp, ps, time_idx, batch_idx, hbank,
                                         per_step, flags);
        reduce_kernel<<<1 + N_PRED, 256, 0, stream>>>(per_step, flags, out);
    } else {
        float* per_step = (float*)d_ws;
        float* flags    = per_step + NTB;
        fk_kernel_f32<<<NTB, 256, 0, stream>>>(lp, ps, time_idx, batch_idx,
                                               per_step, flags);
        reduce_kernel<<<1 + N_PRED, 256, 0, stream>>>(per_step, flags, out);
    }
}

// Round 18
// 44.394 us; speedup vs baseline: 1.9689x; 1.2646x over previous
//
#include <hip/hip_runtime.h>
#include <hip/hip_fp16.h>
#include <math.h>

#define N_PRED 12
#define B      256
#define N_NEG  128
#define D      512
#define NROWS  ((N_PRED + 1) * B)   // 3328 bank rows
#define NTB    (N_PRED * B)         // 3072 (t,b) pairs
#define LOG2E  1.4426950408889634f
#define LN2    0.6931471805599453f
#define BANDF  0.06f                 // candidate band (validated: absmax 0 at R17)

typedef float f2 __attribute__((ext_vector_type(2)));

__device__ __forceinline__ float ex2(float x) { return __builtin_amdgcn_exp2f(x); }

// ---------------- conversion: fp32 bank -> fp16 bank (3.4 MB, L2-resident) --
__global__ __launch_bounds__(256) void conv_kernel(
    const float* __restrict__ lp, const float* __restrict__ ps,
    __half* __restrict__ hbank)
{
    const int e8 = blockIdx.x * 256 + threadIdx.x;  // 8-elem chunk id
    const int e  = e8 * 8;
    const float* src = (e < B * D) ? (lp + e) : (ps + (e - B * D));
    float4 a = ((const float4*)src)[0];
    float4 b = ((const float4*)src)[1];
    union { uint4 u; __half2 h[4]; } o;
    o.h[0] = __floats2half2_rn(a.x, a.y);
    o.h[1] = __floats2half2_rn(a.z, a.w);
    o.h[2] = __floats2half2_rn(b.x, b.y);
    o.h[3] = __floats2half2_rn(b.z, b.w);
    ((uint4*)hbank)[e8] = o.u;
}

// exp-sum over this lane's 32 d-elements of an fp16 row (uint4 chunks q+16j,
// j=0..3: per 16-lane group each load instr covers 4x256B contiguous segs).
__device__ __forceinline__ float fk_half_g(const __half* __restrict__ rowh,
                                           const f2* __restrict__ p2, int q) {
    const uint4* r = (const uint4*)rowh;
    f2 acc = {0.f, 0.f};
#pragma unroll
    for (int j = 0; j < 4; ++j) {
        uint4 w = r[q + 16 * j];
        const __half2* hp = (const __half2*)&w;
        float2 f0 = __half22float2(hp[0]);
        float2 f1 = __half22float2(hp[1]);
        float2 fv = __half22float2(hp[2]);
        float2 f3 = __half22float2(hp[3]);
        f2 m0 = p2[4 * j + 0] * f2{f0.x, f0.y};
        f2 m1 = p2[4 * j + 1] * f2{f1.x, f1.y};
        f2 m2 = p2[4 * j + 2] * f2{fv.x, fv.y};
        f2 m3 = p2[4 * j + 3] * f2{f3.x, f3.y};
        acc += f2{ex2(m0.x), ex2(m0.y)};
        acc += f2{ex2(m1.x), ex2(m1.y)};
        acc += f2{ex2(m2.x), ex2(m2.y)};
        acc += f2{ex2(m3.x), ex2(m3.y)};
    }
    return acc.x + acc.y;
}

// ---------------- main kernel: R11 structure + R17 candidate redo ----------
// One block per (t,b). 4 waves x 64 lanes; 16 lanes/neg (4 groups/wave),
// 8 iters x 4 negs. This exact hot-loop shape measured 48us (R11, session
// best). Grafted improvements: per-neg fk kept in LDS; exact fp32 redo only
// for blocks inside a 6% win/lose band AND only for the 1-4 candidate negs
// (R17), instead of R11's full-128-row redo; no fp32 address staging in the
// hot path.
__global__ __launch_bounds__(256) void fk_kernel_h(
    const float* __restrict__ lp,        // (13,256,512) fp32
    const float* __restrict__ ps,        // (12,256,512) fp32
    const int*   __restrict__ time_idx,  // (12,256,128)
    const int*   __restrict__ batch_idx, // (12,256,128)
    const __half* __restrict__ hbank,    // (3328,512) fp16 bank
    float* __restrict__ per_step,        // (3072)
    float* __restrict__ flags)           // (3072)
{
    const int tb   = blockIdx.x;
    const int t    = tb >> 8;
    const int b    = tb & (B - 1);
    const int tid  = threadIdx.x;
    const int wave = tid >> 6;
    const int lane = tid & 63;
    const int q    = lane & 15;
    const int g    = lane >> 4;

    __shared__ const __half* s_rowh[N_NEG];
    __shared__ float s_fk[N_NEG];
    __shared__ float s_sum[4];
    __shared__ float s_max[4];
    __shared__ int   s_oki[4];
    __shared__ int   s_flag;
    __shared__ float s_thr;

    const int idx_base = (t * B + b) * N_NEG;
    if (tid < N_NEG) {
        const int ti  = time_idx[idx_base + tid];
        const int bi  = batch_idx[idx_base + tid];
        s_rowh[tid] = hbank + (size_t)(ti * B + bi) * D;
    }

    // pred slice, pre-scaled by log2(e): p2[4j+k] = pred pair at elem q*8+j*128+2k
    const float4* pred4 = (const float4*)(lp + ((size_t)(t + 1) * B + b) * D);
    f2 p2[16];
#pragma unroll
    for (int j = 0; j < 4; ++j) {
        float4 pa = pred4[(q + 16 * j) * 2];
        float4 pb = pred4[(q + 16 * j) * 2 + 1];
        p2[4 * j + 0] = f2{pa.x * LOG2E, pa.y * LOG2E};
        p2[4 * j + 1] = f2{pa.z * LOG2E, pa.w * LOG2E};
        p2[4 * j + 2] = f2{pb.x * LOG2E, pb.y * LOG2E};
        p2[4 * j + 3] = f2{pb.z * LOG2E, pb.w * LOG2E};
    }

    // fk_pos from the fp16 bank row for ps[t,b] = bank[t+1, b]
    float fk_pos;
    {
        float s = fk_half_g(hbank + ((size_t)(t + 1) * B + b) * D, p2, q);
#pragma unroll
        for (int off = 1; off < 16; off <<= 1) s += __shfl_xor(s, off, 64);
        fk_pos = s;
    }

    __syncthreads();          // addresses staged

    float negsum = 0.0f;
    float maxfk  = 0.0f;

#pragma unroll 2
    for (int it = 0; it < 8; ++it) {
        const int n = wave * 32 + it * 4 + g;
        float fk = fk_half_g(s_rowh[n], p2, q);
#pragma unroll
        for (int off = 1; off < 16; off <<= 1) fk += __shfl_xor(fk, off, 64);
        negsum += fk;
        maxfk   = fmaxf(maxfk, fk);
        if (q == 0) s_fk[n] = fk;      // uniform in group; one lane writes
    }

    // cross-group combine (offsets 16,32): exact wave sum / max
    float ns = negsum;
#pragma unroll
    for (int off = 16; off < 64; off <<= 1) ns += __shfl_xor(ns, off, 64);
    float mx = maxfk;
#pragma unroll
    for (int off = 16; off < 64; off <<= 1) mx = fmaxf(mx, __shfl_xor(mx, off, 64));

    if (lane == 0) { s_sum[wave] = ns; s_max[wave] = mx; }
    __syncthreads();
    if (tid == 0) {
        float total_neg = (s_sum[0] + s_sum[1]) + (s_sum[2] + s_sum[3]);
        float bmx = fmaxf(fmaxf(s_max[0], s_max[1]), fmaxf(s_max[2], s_max[3]));
        per_step[tb] = (__builtin_amdgcn_logf(fk_pos) -
                        __builtin_amdgcn_logf(fk_pos + total_neg)) * LN2;
        const float band = BANDF * fmaxf(fk_pos, bmx);
        if (bmx > fk_pos + band)      { flags[tb] = 0.0f; s_flag = 0; }
        else if (bmx < fk_pos - band) { flags[tb] = 1.0f; s_flag = 0; }
        else { s_flag = 1; s_thr = fk_pos - band; }
    }
    __syncthreads();

    if (s_flag) {
        // Exact fp32 redo: ONLY candidate negs (fk >= thr), 64 lanes per row.
        float4 pl0 = pred4[lane];
        float4 pl1 = pred4[lane + 64];
        pl0.x *= LOG2E; pl0.y *= LOG2E; pl0.z *= LOG2E; pl0.w *= LOG2E;
        pl1.x *= LOG2E; pl1.y *= LOG2E; pl1.z *= LOG2E; pl1.w *= LOG2E;

        const float4* pr = (const float4*)(ps + ((size_t)t * B + b) * D);
        float4 ya = pr[lane], yb = pr[lane + 64];
        float sp = ex2(pl0.x * ya.x) + ex2(pl0.y * ya.y) + ex2(pl0.z * ya.z) + ex2(pl0.w * ya.w)
                 + ex2(pl1.x * yb.x) + ex2(pl1.y * yb.y) + ex2(pl1.z * yb.z) + ex2(pl1.w * yb.w);
#pragma unroll
        for (int off = 1; off < 64; off <<= 1) sp += __shfl_xor(sp, off, 64);
        const float fkpos32 = sp;

        // candidate mask over this wave's 32 negs (lane n < 32 <-> neg wave*32+n)
        const float thr = s_thr;
        unsigned long long m =
            __ballot((lane < 32) && (s_fk[wave * 32 + lane] >= thr));

        int okx = 1;
        while (m) {
            const int n  = (int)__builtin_ctzll(m);   // 0..31
            m &= m - 1;
            const int nn = wave * 32 + n;
            const int ti = time_idx[idx_base + nn];
            const int bi = batch_idx[idx_base + nn];
            const float* row = (ti == 0) ? (lp + (size_t)bi * D)
                                         : (ps + ((size_t)(ti - 1) * B + bi) * D);
            const float4* r4 = (const float4*)row;
            float4 za = r4[lane], zb = r4[lane + 64];
            float s = ex2(pl0.x * za.x) + ex2(pl0.y * za.y) + ex2(pl0.z * za.z) + ex2(pl0.w * za.w)
                    + ex2(pl1.x * zb.x) + ex2(pl1.y * zb.y) + ex2(pl1.z * zb.z) + ex2(pl1.w * zb.w);
#pragma unroll
            for (int off = 1; off < 64; off <<= 1) s += __shfl_xor(s, off, 64);
            okx &= (fkpos32 > s) ? 1 : 0;
        }
        if (lane == 0) s_oki[wave] = okx;
        __syncthreads();
        if (tid == 0)
            flags[tb] = (float)(s_oki[0] & s_oki[1] & s_oki[2] & s_oki[3]);
    }
}

// ---------------- fallback: proven R5 fp32 kernel (used if ws too small) ---
__global__ __launch_bounds__(256) void fk_kernel_f32(
    const float* __restrict__ lp, const float* __restrict__ ps,
    const int* __restrict__ time_idx, const int* __restrict__ batch_idx,
    float* __restrict__ per_step, float* __restrict__ flags)
{
    const int tb   = blockIdx.x;
    const int t    = tb >> 8;
    const int b    = tb & (B - 1);
    const int tid  = threadIdx.x;
    const int wave = tid >> 6;
    const int lane = tid & 63;
    const int q    = lane & 15;
    const int g    = lane >> 4;

    __shared__ const float* s_row[N_NEG];
    __shared__ float s_sum[4];
    __shared__ int   s_ok[4];

    const int idx_base = (t * B + b) * N_NEG;
    if (tid < N_NEG) {
        const int ti = time_idx[idx_base + tid];
        const int bi = batch_idx[idx_base + tid];
        s_row[tid] = (ti == 0) ? (lp + (size_t)bi * D)
                               : (ps + ((size_t)(ti - 1) * B + bi) * D);
    }

    const float4* pred4 = (const float4*)(lp + ((size_t)(t + 1) * B + b) * D) + q;
    f2 p2[16];
#pragma unroll
    for (int j = 0; j < 8; ++j) {
        float4 v = pred4[j * 16];
        p2[2 * j]     = f2{v.x * LOG2E, v.y * LOG2E};
        p2[2 * j + 1] = f2{v.z * LOG2E, v.w * LOG2E};
    }

    float fk_pos;
    {
        const float4* pos4 = (const float4*)(ps + ((size_t)t * B + b) * D) + q;
        f2 acc = {0.f, 0.f};
#pragma unroll
        for (int j = 0; j < 8; ++j) {
            float4 y = pos4[j * 16];
            f2 m0 = p2[2 * j] * f2{y.x, y.y};
            f2 m1 = p2[2 * j + 1] * f2{y.z, y.w};
            acc += f2{ex2(m0.x), ex2(m0.y)};
            acc += f2{ex2(m1.x), ex2(m1.y)};
        }
        float s = acc.x + acc.y;
#pragma unroll
        for (int off = 1; off < 16; off <<= 1) s += __shfl_xor(s, off, 64);
        fk_pos = s;
    }

    __syncthreads();

    float negsum = 0.0f;
    bool  all_ok = true;
#pragma unroll 2
    for (int it = 0; it < 8; ++it) {
        const int n = wave * 32 + it * 4 + g;
        const float4* row4 = (const float4*)s_row[n] + q;
        f2 acc = {0.f, 0.f};
#pragma unroll
        for (int j = 0; j < 8; ++j) {
            float4 y = row4[j * 16];
            f2 m0 = p2[2 * j] * f2{y.x, y.y};
            f2 m1 = p2[2 * j + 1] * f2{y.z, y.w};
            acc += f2{ex2(m0.x), ex2(m0.y)};
            acc += f2{ex2(m1.x), ex2(m1.y)};
        }
        float fk = acc.x + acc.y;
#pragma unroll
        for (int off = 1; off < 16; off <<= 1) fk += __shfl_xor(fk, off, 64);
        negsum += fk;
        all_ok  = all_ok && (fk_pos > fk);
    }

    const int wave_ok = __all(all_ok ? 1 : 0);
    float ns = negsum;
#pragma unroll
    for (int off = 16; off < 64; off <<= 1) ns += __shfl_xor(ns, off, 64);

    if (lane == 0) { s_sum[wave] = ns; s_ok[wave] = wave_ok; }
    __syncthreads();
    if (tid == 0) {
        float total_neg = (s_sum[0] + s_sum[1]) + (s_sum[2] + s_sum[3]);
        int   ok        = s_ok[0] & s_ok[1] & s_ok[2] & s_ok[3];
        float total     = fk_pos + total_neg;
        per_step[tb] = (__builtin_amdgcn_logf(fk_pos) - __builtin_amdgcn_logf(total)) * LN2;
        flags[tb]    = (float)ok;
    }
}

// ---------------- final reduce --------------------------------------------
__global__ __launch_bounds__(256) void reduce_kernel(
    const float* __restrict__ per_step,
    const float* __restrict__ flags,
    float* __restrict__ out)
{
    const int tid = threadIdx.x;
    const int j   = blockIdx.x;
    __shared__ float sh[4];

    float s = 0.0f;
    if (j == 0) {
#pragma unroll
        for (int t = 0; t < N_PRED; ++t) s += per_step[t * B + tid];
    } else {
        s = flags[(j - 1) * B + tid];
    }
#pragma unroll
    for (int off = 32; off > 0; off >>= 1) s += __shfl_xor(s, off, 64);
    if ((tid & 63) == 0) sh[tid >> 6] = s;
    __syncthreads();
    if (tid == 0) {
        float tot = (sh[0] + sh[1]) + (sh[2] + sh[3]);
        if (j == 0)
            out[0] = tot * (1.0f / ((float)(N_NEG + 1) * N_PRED * B));
        else
            out[j] = tot;
    }
}

extern "C" void kernel_launch(void* const* d_in, const int* in_sizes, int n_in,
                              void* d_out, int out_size, void* d_ws, size_t ws_size,
                              hipStream_t stream) {
    const float* lp        = (const float*)d_in[0];
    const float* ps        = (const float*)d_in[1];
    const int*   time_idx  = (const int*)d_in[2];
    const int*   batch_idx = (const int*)d_in[3];
    float* out = (float*)d_out;

    const size_t hbytes = (size_t)NROWS * D * sizeof(__half);          // 3.4 MB
    const size_t need   = hbytes + 2 * (size_t)NTB * sizeof(float);

    if (ws_size >= need) {
        __half* hbank    = (__half*)d_ws;
        float*  per_step = (float*)((char*)d_ws + hbytes);
        float*  flags    = per_step + NTB;

        conv_kernel<<<NROWS * D / 8 / 256, 256, 0, stream>>>(lp, ps, hbank);
        fk_kernel_h<<<NTB, 256, 0, stream>>>(lp, ps, time_idx, batch_idx,
                                             hbank, per_step, flags);
        reduce_kernel<<<1 + N_PRED, 256, 0, stream>>>(per_step, flags, out);
    } else {
        float* per_step = (float*)d_ws;
        float* flags    = per_step + NTB;
        fk_kernel_f32<<<NTB, 256, 0, stream>>>(lp, ps, time_idx, batch_idx,
                                               per_step, flags);
        reduce_kernel<<<1 + N_PRED, 256, 0, stream>>>(per_step, flags, out);
    }
}